// Round 11
// baseline (243.234 us; speedup 1.0000x reference)
//
#include <hip/hip_runtime.h>
#include <stdint.h>
#include <stddef.h>

typedef unsigned short u16;
typedef __attribute__((ext_vector_type(8))) short s16x8;    // bf16 MFMA A/B frag (4 VGPR)
typedef __attribute__((ext_vector_type(8))) unsigned short u16x8;
typedef __attribute__((ext_vector_type(4))) unsigned short u16x4;
typedef __attribute__((ext_vector_type(4))) float f32x4;

typedef __attribute__((address_space(3))) void* as3_void_p;
typedef const __attribute__((address_space(1))) void* as1_cvoid_p;

#define GLD16(gp, lp) __builtin_amdgcn_global_load_lds((as1_cvoid_p)(gp), (as3_void_p)(lp), 16, 0, 0)

enum {
  NS = 2048, NF = 512, NH = 512, NW = 5,
  NROW = 32768,                    // B*S
  K2 = NW * NF,                    // 2560
  XBLOCKS = NROW * NF / 4 / 256,   // 16384
  W_ELEMS = 1024 * 512 + 512 * K2, // 1,835,008
  WBLOCKS = (W_ELEMS + 255) / 256  // 7168
};

__device__ __forceinline__ u16 f2bf(float f) {
  unsigned u = __float_as_uint(f);
  u += 0x7FFFu + ((u >> 16) & 1u);     // round-to-nearest-even
  return (u16)(u >> 16);
}
__device__ __forceinline__ float bf2f(u16 v) {
  return __uint_as_float(((unsigned)v) << 16);
}

// ---------------- merged conversion kernel ----------------

__global__ __launch_bounds__(256) void cvt_all(const float* __restrict__ X,
                                               const float* __restrict__ Wq,
                                               const float* __restrict__ Wk,
                                               const float* __restrict__ cnnW,
                                               u16* __restrict__ Xb,
                                               u16* __restrict__ Wt1,
                                               u16* __restrict__ Wt2) {
  int b = blockIdx.x;
  if (b < XBLOCKS) {
    int i = b * 256 + threadIdx.x;                 // 0 .. NROW*NF/4
    f32x4 v = ((const f32x4*)X)[i];
    u16x4 o;
    o.x = f2bf(v.x); o.y = f2bf(v.y); o.z = f2bf(v.z); o.w = f2bf(v.w);
    ((u16x4*)Xb)[i] = o;
  } else {
    int i = (b - XBLOCKS) * 256 + threadIdx.x;     // 0 .. W_ELEMS
    if (i >= W_ELEMS) return;
    if (i < 1024 * 512) {
      int j = i >> 9, f = i & 511;
      float v = (j < 512) ? Wq[(size_t)f * 512 + j] : Wk[(size_t)f * 512 + (j - 512)];
      Wt1[i] = f2bf(v);
    } else {
      int t = i - 1024 * 512;                      // < 512*2560
      int h = t / K2, k = t % K2;
      Wt2[t] = f2bf(cnnW[(size_t)k * 512 + h]);
    }
  }
}

// ---------------- GEMM1: QKb[n][0:1024] = Xb @ Wt1^T  (bf16 out) ----------------
// 256x128 block tile, 8 waves (2x4, wave tile 128x32), BK=64, 3-slot LDS ring,
// depth-2 prefetch with counted vmcnt(6), ONE raw barrier per K-tile.
// T2 XOR-swizzle via pre-swizzled global source (rule #21).

__global__ __launch_bounds__(512, 2) void gemm_qk(const u16* __restrict__ Xb,
                                                  const u16* __restrict__ Wt1,
                                                  u16* __restrict__ QKb) {
  __shared__ u16 As[3][256 * 64];                  // 3 x 32 KB
  __shared__ u16 Bs[3][128 * 64];                  // 3 x 16 KB
  const int tid  = threadIdx.x;
  const int lane = tid & 63, wid = tid >> 6;
  const int wr = wid >> 2, wc = wid & 3;           // 2 x 4 wave grid
  const int fr = lane & 15, fq = lane >> 4;
  // XCD-chunk swizzle: 1024 blocks (128 row-panels x 8 col-blocks)
  const int wgid = (blockIdx.x & 7) * 128 + (blockIdx.x >> 3);
  const int brow = (wgid >> 3) * 256;
  const int bcol = (wgid & 7) * 128;

  const int rsub = tid >> 3;                                   // 0..63
  const int cbyte = (((tid & 7) ^ (rsub & 7)) << 4);           // swizzled source column byte
  const char* gA[4];
  const char* gB[2];
#pragma unroll
  for (int g = 0; g < 4; ++g)
    gA[g] = (const char*)(Xb + (size_t)(brow + g * 64 + rsub) * NF) + cbyte;
#pragma unroll
  for (int g = 0; g < 2; ++g)
    gB[g] = (const char*)(Wt1 + (size_t)(bcol + g * 64 + rsub) * NF) + cbyte;

  f32x4 acc[8][2] = {};

  // stage K-tile s (6 GLD16) into ring slot `slot`
  auto STAGE = [&](int s, int slot) {
    const int ko = s * 128;                        // byte offset along K
    char* ab = (char*)&As[slot][0];
    char* bb = (char*)&Bs[slot][0];
#pragma unroll
    for (int g = 0; g < 4; ++g) GLD16(gA[g] + ko, ab + g * 8192 + tid * 16);
#pragma unroll
    for (int g = 0; g < 2; ++g) GLD16(gB[g] + ko, bb + g * 8192 + tid * 16);
  };

  STAGE(0, 0);
  STAGE(1, 1);

  int rd = 0;
  for (int it = 0; it < 8; ++it) {
    if (it < 7) asm volatile("s_waitcnt vmcnt(6)" ::: "memory");  // tile it done; it+1 in flight
    else        asm volatile("s_waitcnt vmcnt(0)" ::: "memory");
    __builtin_amdgcn_s_barrier();                  // tile it published; slot of it-1 fully dead
    if (it + 2 < 8) {
      int st = rd + 2; if (st >= 3) st -= 3;
      STAGE(it + 2, st);                           // deep prefetch into dead slot
    }
    const char* Ab = (const char*)&As[rd][0];
    const char* Bb = (const char*)&Bs[rd][0];
#pragma unroll
    for (int kk = 0; kk < 2; ++kk) {
      s16x8 bfr[2];
#pragma unroll
      for (int n = 0; n < 2; ++n) {
        int row = wc * 32 + n * 16 + fr;
        bfr[n] = *(const s16x8*)(Bb + row * 128 + ((kk * 64 + fq * 16) ^ ((row & 7) << 4)));
      }
#pragma unroll
      for (int m = 0; m < 8; ++m) {
        int row = wr * 128 + m * 16 + fr;
        s16x8 af = *(const s16x8*)(Ab + row * 128 + ((kk * 64 + fq * 16) ^ ((row & 7) << 4)));
        acc[m][0] = __builtin_amdgcn_mfma_f32_16x16x32_bf16(af, bfr[0], acc[m][0], 0, 0, 0);
        acc[m][1] = __builtin_amdgcn_mfma_f32_16x16x32_bf16(af, bfr[1], acc[m][1], 0, 0, 0);
      }
    }
    rd = rd + 1; if (rd >= 3) rd = 0;
  }

#pragma unroll
  for (int m = 0; m < 8; ++m)
#pragma unroll
    for (int n = 0; n < 2; ++n)
#pragma unroll
      for (int r = 0; r < 4; ++r) {
        int row = brow + wr * 128 + m * 16 + fq * 4 + r;
        int col = bcol + wc * 32 + n * 16 + fr;
        QKb[(size_t)row * 1024 + col] = f2bf(acc[m][n][r]);
      }
}

// ---------------- scores + softmax -> att[n][5] ----------------

__global__ __launch_bounds__(256) void scores_att(const u16* __restrict__ QKb,
                                                  const float* __restrict__ vatt,
                                                  float* __restrict__ att) {
  const int lane = threadIdx.x & 63;
  const int wid  = threadIdx.x >> 6;
  const int wgid = (blockIdx.x & 7) * 1024 + (blockIdx.x >> 3);   // 8192 blocks chunked
  const int n = wgid * 4 + wid;
  const int s = n & (NS - 1);
  const int h0 = lane * 8;

  u16x8 qv = *(const u16x8*)(QKb + (size_t)n * 1024 + h0);
  f32x4 va0 = *(const f32x4*)(vatt + h0);
  f32x4 va1 = *(const f32x4*)(vatt + h0 + 4);
  float q[8], vv[8];
#pragma unroll
  for (int j = 0; j < 8; ++j) q[j] = bf2f(qv[j]);
  vv[0] = va0.x; vv[1] = va0.y; vv[2] = va0.z; vv[3] = va0.w;
  vv[4] = va1.x; vv[5] = va1.y; vv[6] = va1.z; vv[7] = va1.w;

  float sc[5];
#pragma unroll
  for (int w = 0; w < 5; ++w) {
    int sp = s + w - 2;
    u16x8 kv = {0, 0, 0, 0, 0, 0, 0, 0};
    if (sp >= 0 && sp < NS)
      kv = *(const u16x8*)(QKb + (size_t)(n + w - 2) * 1024 + 512 + h0);
    float acc = 0.f;
#pragma unroll
    for (int j = 0; j < 8; ++j) {
      float x = q[j] + bf2f(kv[j]);
      x = fminf(fmaxf(x, -15.f), 15.f);
      float e = __expf(2.f * x);
      acc += vv[j] * ((e - 1.f) / (e + 1.f));     // tanh(x)
    }
    sc[w] = acc;
  }
#pragma unroll
  for (int w = 0; w < 5; ++w)
#pragma unroll
    for (int o = 32; o > 0; o >>= 1)
      sc[w] += __shfl_xor(sc[w], o, 64);

  if (lane == 0) {
    float m = sc[0];
#pragma unroll
    for (int w = 1; w < 5; ++w) m = fmaxf(m, sc[w]);
    float e[5], sum = 0.f;
#pragma unroll
    for (int w = 0; w < 5; ++w) { e[w] = __expf(sc[w] - m); sum += e[w]; }
    float inv = 1.f / sum;
#pragma unroll
    for (int w = 0; w < 5; ++w) att[(size_t)n * 5 + w] = e[w] * inv;
  }
}

// ---------------- GEMM2 (fold + 3-slot deep pipeline) ----------------
// out[n][h] = b[h] + sum_w att[n][w]*(X[n+w-2]@W_w)[h]
// 256x128 block tile, 8 waves (2x4, wave tile 128x32), BK=64, 3-slot LDS ring,
// depth-2 prefetch (vmcnt(6)), ONE raw barrier per K-tile. Fold after each w's
// 8 K-tiles (att weight 0 for seq-OOB rows; A row indices clamped in-bounds).

__global__ __launch_bounds__(512, 2) void gemm_out(const u16* __restrict__ Xb,
                                                   const u16* __restrict__ Wt2,
                                                   const float* __restrict__ att,
                                                   const float* __restrict__ cnnb,
                                                   float* __restrict__ out) {
  __shared__ u16 As[3][256 * 64];                  // 3 x 32 KB
  __shared__ u16 Bs[3][128 * 64];                  // 3 x 16 KB
  __shared__ float att_s[256 * 5];
  const int tid  = threadIdx.x;
  const int lane = tid & 63, wid = tid >> 6;
  const int wr = wid >> 2, wc = wid & 3;           // 2 x 4 wave grid, wave tile 128x32
  const int fr = lane & 15, fq = lane >> 4;
  // XCD-chunk swizzle: 512 blocks (128 row-panels x 4 col-blocks)
  const int wgid = (blockIdx.x & 7) * 64 + (blockIdx.x >> 3);
  const int brow = (wgid >> 2) * 256;
  const int bcol = (wgid & 3) * 128;

  if (tid < 256) {
    int s = (brow + tid) & (NS - 1);
#pragma unroll
    for (int w = 0; w < 5; ++w) {
      int sp = s + w - 2;
      att_s[tid * 5 + w] = (sp >= 0 && sp < NS) ? att[(size_t)(brow + tid) * 5 + w] : 0.f;
    }
  }

  const int rsub = tid >> 3;                                   // 0..63
  const int cbyte = (((tid & 7) ^ (rsub & 7)) << 4);           // swizzled source column byte
  const char* gB[2];
#pragma unroll
  for (int g = 0; g < 2; ++g)
    gB[g] = (const char*)(Wt2 + (size_t)(bcol + g * 64 + rsub) * K2) + cbyte;

  const char* gA[4];
  auto setA = [&](int w) {                         // per-w A bases (clamped)
#pragma unroll
    for (int g = 0; g < 4; ++g) {
      int r = brow + g * 64 + rsub + w - 2;
      r = r < 0 ? 0 : (r >= NROW ? NROW - 1 : r);
      gA[g] = (const char*)(Xb + (size_t)r * NF) + cbyte;
    }
  };

  // stage K-tile s into ring slot `slot`; A offset (s&7)*128 (w-base in gA), B offset s*128
  auto STAGE = [&](int s, int slot) {
    const int ka = (s & 7) * 128;
    const int kb = s * 128;                        // = w*1024 + kt*128
    char* ab = (char*)&As[slot][0];
    char* bb = (char*)&Bs[slot][0];
#pragma unroll
    for (int g = 0; g < 4; ++g) GLD16(gA[g] + ka, ab + g * 8192 + tid * 16);
#pragma unroll
    for (int g = 0; g < 2; ++g) GLD16(gB[g] + kb, bb + g * 8192 + tid * 16);
  };

  f32x4 acc[8][2] = {};
  f32x4 accOut[8][2] = {};

  setA(0);
  STAGE(0, 0);
  STAGE(1, 1);

  int rd = 0;
  for (int it = 0; it < 40; ++it) {
    if (it < 39) asm volatile("s_waitcnt vmcnt(6)" ::: "memory");  // tile it done; it+1 in flight
    else         asm volatile("s_waitcnt vmcnt(0)" ::: "memory");
    __builtin_amdgcn_s_barrier();                  // tile it published; slot of it-1 fully dead
    {
      int s = it + 2;
      if (s < 40) {
        if ((s & 7) == 0) setA(s >> 3);            // new w for the staged tile
        int st = rd + 2; if (st >= 3) st -= 3;
        STAGE(s, st);
      }
    }
    const char* Ab = (const char*)&As[rd][0];
    const char* Bb = (const char*)&Bs[rd][0];
#pragma unroll
    for (int kk = 0; kk < 2; ++kk) {
      s16x8 bfr[2];
#pragma unroll
      for (int n = 0; n < 2; ++n) {
        int row = wc * 32 + n * 16 + fr;
        bfr[n] = *(const s16x8*)(Bb + row * 128 + ((kk * 64 + fq * 16) ^ ((row & 7) << 4)));
      }
#pragma unroll
      for (int m = 0; m < 8; ++m) {
        int row = wr * 128 + m * 16 + fr;
        s16x8 af = *(const s16x8*)(Ab + row * 128 + ((kk * 64 + fq * 16) ^ ((row & 7) << 4)));
        acc[m][0] = __builtin_amdgcn_mfma_f32_16x16x32_bf16(af, bfr[0], acc[m][0], 0, 0, 0);
        acc[m][1] = __builtin_amdgcn_mfma_f32_16x16x32_bf16(af, bfr[1], acc[m][1], 0, 0, 0);
      }
    }
    if ((it & 7) == 7) {
      // fold: accOut += att[row][w] * acc; acc = 0  (registers + att_s only)
      int w = it >> 3;
#pragma unroll
      for (int m = 0; m < 8; ++m) {
        float a0 = att_s[(wr * 128 + m * 16 + fq * 4 + 0) * 5 + w];
        float a1 = att_s[(wr * 128 + m * 16 + fq * 4 + 1) * 5 + w];
        float a2 = att_s[(wr * 128 + m * 16 + fq * 4 + 2) * 5 + w];
        float a3 = att_s[(wr * 128 + m * 16 + fq * 4 + 3) * 5 + w];
#pragma unroll
        for (int n = 0; n < 2; ++n) {
          accOut[m][n][0] += a0 * acc[m][n][0];
          accOut[m][n][1] += a1 * acc[m][n][1];
          accOut[m][n][2] += a2 * acc[m][n][2];
          accOut[m][n][3] += a3 * acc[m][n][3];
          acc[m][n] = f32x4{0.f, 0.f, 0.f, 0.f};
        }
      }
    }
    rd = rd + 1; if (rd >= 3) rd = 0;
  }

#pragma unroll
  for (int m = 0; m < 8; ++m)
#pragma unroll
    for (int n = 0; n < 2; ++n)
#pragma unroll
      for (int r = 0; r < 4; ++r) {
        int row = brow + wr * 128 + m * 16 + fq * 4 + r;
        int col = bcol + wc * 32 + n * 16 + fr;
        out[(size_t)row * NH + col] = accOut[m][n][r] + cnnb[col];
      }
}

// ---------------- launch ----------------

extern "C" void kernel_launch(void* const* d_in, const int* in_sizes, int n_in,
                              void* d_out, int out_size, void* d_ws, size_t ws_size,
                              hipStream_t stream) {
  const float* X    = (const float*)d_in[0];
  const float* Wq   = (const float*)d_in[1];
  const float* Wk   = (const float*)d_in[2];
  const float* vatt = (const float*)d_in[3];
  const float* cnnW = (const float*)d_in[4];
  const float* cnnb = (const float*)d_in[5];
  float* out = (float*)d_out;

  char* ws = (char*)d_ws;
  u16*   Xb  = (u16*)ws;                            // 32768*512*2  =  33,554,432 B
  u16*   Wt1 = (u16*)(ws + 33554432);               // 1024*512*2   =   1,048,576 B
  u16*   Wt2 = (u16*)(ws + 34603008);               // 512*2560*2   =   2,621,440 B
  u16*   QKb = (u16*)(ws + 37224448);               // 32768*1024*2 =  67,108,864 B
  float* att = (float*)(ws + 104333312);            // 32768*5*4    =     655,360 B
                                                    // total ~105 MB

  cvt_all<<<dim3(XBLOCKS + WBLOCKS), dim3(256), 0, stream>>>(X, Wq, Wk, cnnW, Xb, Wt1, Wt2);
  gemm_qk<<<dim3(1024), dim3(512), 0, stream>>>(Xb, Wt1, QKb);
  scores_att<<<dim3(NROW / 4), dim3(256), 0, stream>>>(QKb, vatt, att);
  gemm_out<<<dim3(512), dim3(512), 0, stream>>>(Xb, Wt2, att, cnnb, out);
}

// Round 12
// 198.974 us; speedup vs baseline: 1.2224x; 1.2224x over previous
//
#include <hip/hip_runtime.h>
#include <stdint.h>
#include <stddef.h>

typedef unsigned short u16;
typedef __attribute__((ext_vector_type(8))) short s16x8;    // bf16 MFMA A/B frag (4 VGPR)
typedef __attribute__((ext_vector_type(8))) unsigned short u16x8;
typedef __attribute__((ext_vector_type(4))) unsigned short u16x4;
typedef __attribute__((ext_vector_type(4))) float f32x4;

typedef __attribute__((address_space(3))) void* as3_void_p;
typedef const __attribute__((address_space(1))) void* as1_cvoid_p;

#define GLD16(gp, lp) __builtin_amdgcn_global_load_lds((as1_cvoid_p)(gp), (as3_void_p)(lp), 16, 0, 0)

enum {
  NS = 2048, NF = 512, NH = 512, NW = 5,
  NROW = 32768,                    // B*S
  K2 = NW * NF,                    // 2560
  XBLOCKS = NROW * NF / 4 / 256,   // 16384
  W_ELEMS = 1024 * 512 + 512 * K2, // 1,835,008
  WBLOCKS = (W_ELEMS + 255) / 256  // 7168
};

__device__ __forceinline__ u16 f2bf(float f) {
  unsigned u = __float_as_uint(f);
  u += 0x7FFFu + ((u >> 16) & 1u);     // round-to-nearest-even
  return (u16)(u >> 16);
}
__device__ __forceinline__ float bf2f(u16 v) {
  return __uint_as_float(((unsigned)v) << 16);
}

// ---------------- merged conversion kernel ----------------

__global__ __launch_bounds__(256) void cvt_all(const float* __restrict__ X,
                                               const float* __restrict__ Wq,
                                               const float* __restrict__ Wk,
                                               const float* __restrict__ cnnW,
                                               u16* __restrict__ Xb,
                                               u16* __restrict__ Wt1,
                                               u16* __restrict__ Wt2) {
  int b = blockIdx.x;
  if (b < XBLOCKS) {
    int i = b * 256 + threadIdx.x;                 // 0 .. NROW*NF/4
    f32x4 v = ((const f32x4*)X)[i];
    u16x4 o;
    o.x = f2bf(v.x); o.y = f2bf(v.y); o.z = f2bf(v.z); o.w = f2bf(v.w);
    ((u16x4*)Xb)[i] = o;
  } else {
    int i = (b - XBLOCKS) * 256 + threadIdx.x;     // 0 .. W_ELEMS
    if (i >= W_ELEMS) return;
    if (i < 1024 * 512) {
      int j = i >> 9, f = i & 511;
      float v = (j < 512) ? Wq[(size_t)f * 512 + j] : Wk[(size_t)f * 512 + (j - 512)];
      Wt1[i] = f2bf(v);
    } else {
      int t = i - 1024 * 512;                      // < 512*2560
      int h = t / K2, k = t % K2;
      Wt2[t] = f2bf(cnnW[(size_t)k * 512 + h]);
    }
  }
}

// ---------------- GEMM1: QKb[n][0:1024] = Xb @ Wt1^T  (bf16 out) ----------------
// 128x128 block tile, 4 waves (2x2, wave tile 64x64 -> LDS bytes/FLOP 3.1% vs 4.7%),
// BK=64, single-buffer, 2-barrier K-step, 3 blocks/CU. T2 XOR-swizzle (rule #21).

__global__ __launch_bounds__(256, 3) void gemm_qk(const u16* __restrict__ Xb,
                                                  const u16* __restrict__ Wt1,
                                                  u16* __restrict__ QKb) {
  __shared__ u16 As[128 * 64];                     // 16 KB
  __shared__ u16 Bs[128 * 64];                     // 16 KB
  const int tid  = threadIdx.x;
  const int lane = tid & 63, wid = tid >> 6;
  const int wr = wid >> 1, wc = wid & 1;           // 2 x 2 wave grid, wave tile 64x64
  const int fr = lane & 15, fq = lane >> 4;
  // XCD-chunk swizzle: 2048 blocks, one XCD keeps contiguous row-panels
  const int wgid = (blockIdx.x & 7) * 256 + (blockIdx.x >> 3);
  const int brow = (wgid >> 3) * 128;
  const int bcol = (wgid & 7) * 128;

  // staging: 256 threads, 4 passes of 4KB per tile; row = p*32 + (tid>>3)
  const int rsub = tid >> 3;                                   // 0..31
  const int cbyte = (((tid & 7) ^ (rsub & 7)) << 4);           // swizzled source column byte
  const char* gA[4];
  const char* gB[4];
#pragma unroll
  for (int p = 0; p < 4; ++p) {
    gA[p] = (const char*)(Xb  + (size_t)(brow + p * 32 + rsub) * NF) + cbyte;
    gB[p] = (const char*)(Wt1 + (size_t)(bcol + p * 32 + rsub) * NF) + cbyte;
  }

  f32x4 acc[4][4] = {};

  for (int kt = 0; kt < 8; ++kt) {
    const int ko = kt * 128;
#pragma unroll
    for (int p = 0; p < 4; ++p) GLD16(gA[p] + ko, (char*)As + p * 4096 + tid * 16);
#pragma unroll
    for (int p = 0; p < 4; ++p) GLD16(gB[p] + ko, (char*)Bs + p * 4096 + tid * 16);
    __syncthreads();
#pragma unroll
    for (int kk = 0; kk < 2; ++kk) {
      s16x8 af[4], bfr[4];
#pragma unroll
      for (int m = 0; m < 4; ++m) {
        int row = wr * 64 + m * 16 + fr;
        af[m] = *(const s16x8*)((const char*)As + row * 128 + ((kk * 64 + fq * 16) ^ ((row & 7) << 4)));
      }
#pragma unroll
      for (int n = 0; n < 4; ++n) {
        int row = wc * 64 + n * 16 + fr;
        bfr[n] = *(const s16x8*)((const char*)Bs + row * 128 + ((kk * 64 + fq * 16) ^ ((row & 7) << 4)));
      }
#pragma unroll
      for (int m = 0; m < 4; ++m)
#pragma unroll
        for (int n = 0; n < 4; ++n)
          acc[m][n] = __builtin_amdgcn_mfma_f32_16x16x32_bf16(af[m], bfr[n], acc[m][n], 0, 0, 0);
    }
    __syncthreads();
  }

#pragma unroll
  for (int m = 0; m < 4; ++m)
#pragma unroll
    for (int n = 0; n < 4; ++n)
#pragma unroll
      for (int r = 0; r < 4; ++r) {
        int row = brow + wr * 64 + m * 16 + fq * 4 + r;
        int col = bcol + wc * 64 + n * 16 + fr;
        QKb[(size_t)row * 1024 + col] = f2bf(acc[m][n][r]);
      }
}

// ---------------- scores + softmax -> att[n][5] ----------------

__global__ __launch_bounds__(256) void scores_att(const u16* __restrict__ QKb,
                                                  const float* __restrict__ vatt,
                                                  float* __restrict__ att) {
  const int lane = threadIdx.x & 63;
  const int wid  = threadIdx.x >> 6;
  const int wgid = (blockIdx.x & 7) * 1024 + (blockIdx.x >> 3);   // 8192 blocks chunked
  const int n = wgid * 4 + wid;
  const int s = n & (NS - 1);
  const int h0 = lane * 8;

  u16x8 qv = *(const u16x8*)(QKb + (size_t)n * 1024 + h0);
  f32x4 va0 = *(const f32x4*)(vatt + h0);
  f32x4 va1 = *(const f32x4*)(vatt + h0 + 4);
  float q[8], vv[8];
#pragma unroll
  for (int j = 0; j < 8; ++j) q[j] = bf2f(qv[j]);
  vv[0] = va0.x; vv[1] = va0.y; vv[2] = va0.z; vv[3] = va0.w;
  vv[4] = va1.x; vv[5] = va1.y; vv[6] = va1.z; vv[7] = va1.w;

  float sc[5];
#pragma unroll
  for (int w = 0; w < 5; ++w) {
    int sp = s + w - 2;
    u16x8 kv = {0, 0, 0, 0, 0, 0, 0, 0};
    if (sp >= 0 && sp < NS)
      kv = *(const u16x8*)(QKb + (size_t)(n + w - 2) * 1024 + 512 + h0);
    float acc = 0.f;
#pragma unroll
    for (int j = 0; j < 8; ++j) {
      float x = q[j] + bf2f(kv[j]);
      x = fminf(fmaxf(x, -15.f), 15.f);
      float e = __expf(2.f * x);
      acc += vv[j] * ((e - 1.f) / (e + 1.f));     // tanh(x)
    }
    sc[w] = acc;
  }
#pragma unroll
  for (int w = 0; w < 5; ++w)
#pragma unroll
    for (int o = 32; o > 0; o >>= 1)
      sc[w] += __shfl_xor(sc[w], o, 64);

  if (lane == 0) {
    float m = sc[0];
#pragma unroll
    for (int w = 1; w < 5; ++w) m = fmaxf(m, sc[w]);
    float e[5], sum = 0.f;
#pragma unroll
    for (int w = 0; w < 5; ++w) { e[w] = __expf(sc[w] - m); sum += e[w]; }
    float inv = 1.f / sum;
#pragma unroll
    for (int w = 0; w < 5; ++w) att[(size_t)n * 5 + w] = e[w] * inv;
  }
}

// ---------------- GEMM2 (fold + counted-vmcnt, 64x64 wave tiles) ----------------
// out[n][h] = b[h] + sum_w att[n][w]*(X[n+w-2]@W_w)[h]
// 128x128 block tile, 4 waves (2x2, wave tile 64x64), BK=64, double-buffered LDS,
// r10-proven counted s_waitcnt vmcnt(8): next tile's 8 loads stay in flight across
// both raw barriers. Fold after each w's 8 K-tiles (att weight 0 for seq-OOB rows).

__global__ __launch_bounds__(256, 2) void gemm_out(const u16* __restrict__ Xb,
                                                   const u16* __restrict__ Wt2,
                                                   const float* __restrict__ att,
                                                   const float* __restrict__ cnnb,
                                                   float* __restrict__ out) {
  __shared__ u16 As[2][128 * 64];                  // 2 x 16 KB
  __shared__ u16 Bs[2][128 * 64];                  // 2 x 16 KB
  __shared__ float att_s[128 * 5];
  const int tid  = threadIdx.x;
  const int lane = tid & 63, wid = tid >> 6;
  const int wr = wid >> 1, wc = wid & 1;           // 2 x 2 wave grid, wave tile 64x64
  const int fr = lane & 15, fq = lane >> 4;
  // XCD-chunk swizzle: 1024 blocks, contiguous row-panels per XCD (col-fast within)
  const int wgid = (blockIdx.x & 7) * 128 + (blockIdx.x >> 3);
  const int brow = (wgid >> 2) * 128;
  const int bcol = (wgid & 3) * 128;

  if (tid < 128) {
    int s = (brow + tid) & (NS - 1);
#pragma unroll
    for (int w = 0; w < 5; ++w) {
      int sp = s + w - 2;
      att_s[tid * 5 + w] = (sp >= 0 && sp < NS) ? att[(size_t)(brow + tid) * 5 + w] : 0.f;
    }
  }

  // staging: 256 threads, 4 passes of 4KB per tile; row = p*32 + (tid>>3)
  const int rsub = tid >> 3;                                   // 0..31
  const int cbyte = (((tid & 7) ^ (rsub & 7)) << 4);           // swizzled source column byte
  const char* gB[4];
#pragma unroll
  for (int p = 0; p < 4; ++p)
    gB[p] = (const char*)(Wt2 + (size_t)(bcol + p * 32 + rsub) * K2) + cbyte;

  // per-w A row base (clamped; invalid rows get fold weight 0)
  auto abase = [&](int w, int p) -> const char* {
    int g = brow + p * 32 + rsub + w - 2;
    g = g < 0 ? 0 : (g >= NROW ? NROW - 1 : g);
    return (const char*)(Xb + (size_t)g * NF) + cbyte;
  };

  f32x4 acc[4][4] = {};
  f32x4 accOut[4][4] = {};

  const char* gA[4];
#pragma unroll
  for (int p = 0; p < 4; ++p) gA[p] = abase(0, p);

  // prologue: stage (w=0, kt=0) into buf 0; single full drain (also covers att_s)
#pragma unroll
  for (int p = 0; p < 4; ++p) GLD16(gA[p], (char*)As[0] + p * 4096 + tid * 16);
#pragma unroll
  for (int p = 0; p < 4; ++p) GLD16(gB[p], (char*)Bs[0] + p * 4096 + tid * 16);
  __syncthreads();

  int cur = 0;
  for (int w = 0; w < 5; ++w) {
    const char* nA[4];
#pragma unroll
    for (int p = 0; p < 4; ++p) nA[p] = (w < 4) ? abase(w + 1, p) : gA[p];

    for (int kt = 0; kt < 8; ++kt) {
      const bool last = (w == 4) && (kt == 7);
      const int nb = cur ^ 1;
      if (!last) {
        char* ab = (char*)As[nb];
        char* bb = (char*)Bs[nb];
        if (kt < 7) {                              // stage (w, kt+1)
          const int ko = (kt + 1) * 128;
          const int kb = w * 1024 + (kt + 1) * 128;
#pragma unroll
          for (int p = 0; p < 4; ++p) GLD16(gA[p] + ko, ab + p * 4096 + tid * 16);
#pragma unroll
          for (int p = 0; p < 4; ++p) GLD16(gB[p] + kb, bb + p * 4096 + tid * 16);
        } else {                                   // stage (w+1, kt=0)
          const int kb = (w + 1) * 1024;
#pragma unroll
          for (int p = 0; p < 4; ++p) GLD16(nA[p], ab + p * 4096 + tid * 16);
#pragma unroll
          for (int p = 0; p < 4; ++p) GLD16(gB[p] + kb, bb + p * 4096 + tid * 16);
        }
        asm volatile("s_waitcnt vmcnt(8)" ::: "memory");   // tile t done; t+1 in flight
      } else {
        asm volatile("s_waitcnt vmcnt(0)" ::: "memory");   // final tile
      }
      __builtin_amdgcn_s_barrier();                // all waves have tile t in LDS

      const char* Ab = (const char*)As[cur];
      const char* Bb = (const char*)Bs[cur];
#pragma unroll
      for (int kk = 0; kk < 2; ++kk) {
        s16x8 af[4], bfr[4];
#pragma unroll
        for (int m = 0; m < 4; ++m) {
          int row = wr * 64 + m * 16 + fr;
          af[m] = *(const s16x8*)(Ab + row * 128 + ((kk * 64 + fq * 16) ^ ((row & 7) << 4)));
        }
#pragma unroll
        for (int n = 0; n < 4; ++n) {
          int row = wc * 64 + n * 16 + fr;
          bfr[n] = *(const s16x8*)(Bb + row * 128 + ((kk * 64 + fq * 16) ^ ((row & 7) << 4)));
        }
        asm volatile("s_waitcnt lgkmcnt(0)" ::: "memory");
        __builtin_amdgcn_sched_barrier(0);         // rule #18: pin MFMA after the wait
#pragma unroll
        for (int m = 0; m < 4; ++m)
#pragma unroll
          for (int n = 0; n < 4; ++n)
            acc[m][n] = __builtin_amdgcn_mfma_f32_16x16x32_bf16(af[m], bfr[n], acc[m][n], 0, 0, 0);
      }
      if (kt == 7) {
        // fold: accOut += att[row][w] * acc; acc = 0  (registers + att_s only)
#pragma unroll
        for (int m = 0; m < 4; ++m) {
          float a0 = att_s[(wr * 64 + m * 16 + fq * 4 + 0) * 5 + w];
          float a1 = att_s[(wr * 64 + m * 16 + fq * 4 + 1) * 5 + w];
          float a2 = att_s[(wr * 64 + m * 16 + fq * 4 + 2) * 5 + w];
          float a3 = att_s[(wr * 64 + m * 16 + fq * 4 + 3) * 5 + w];
#pragma unroll
          for (int n = 0; n < 4; ++n) {
            accOut[m][n][0] += a0 * acc[m][n][0];
            accOut[m][n][1] += a1 * acc[m][n][1];
            accOut[m][n][2] += a2 * acc[m][n][2];
            accOut[m][n][3] += a3 * acc[m][n][3];
            acc[m][n] = f32x4{0.f, 0.f, 0.f, 0.f};
          }
        }
      }
      __builtin_amdgcn_s_barrier();                // my ds_reads done -> buf reusable
      cur ^= 1;
    }
#pragma unroll
    for (int p = 0; p < 4; ++p) gA[p] = nA[p];
  }

#pragma unroll
  for (int m = 0; m < 4; ++m)
#pragma unroll
    for (int n = 0; n < 4; ++n)
#pragma unroll
      for (int r = 0; r < 4; ++r) {
        int row = brow + wr * 64 + m * 16 + fq * 4 + r;
        int col = bcol + wc * 64 + n * 16 + fr;
        out[(size_t)row * NH + col] = accOut[m][n][r] + cnnb[col];
      }
}

// ---------------- launch ----------------

extern "C" void kernel_launch(void* const* d_in, const int* in_sizes, int n_in,
                              void* d_out, int out_size, void* d_ws, size_t ws_size,
                              hipStream_t stream) {
  const float* X    = (const float*)d_in[0];
  const float* Wq   = (const float*)d_in[1];
  const float* Wk   = (const float*)d_in[2];
  const float* vatt = (const float*)d_in[3];
  const float* cnnW = (const float*)d_in[4];
  const float* cnnb = (const float*)d_in[5];
  float* out = (float*)d_out;

  char* ws = (char*)d_ws;
  u16*   Xb  = (u16*)ws;                            // 32768*512*2  =  33,554,432 B
  u16*   Wt1 = (u16*)(ws + 33554432);               // 1024*512*2   =   1,048,576 B
  u16*   Wt2 = (u16*)(ws + 34603008);               // 512*2560*2   =   2,621,440 B
  u16*   QKb = (u16*)(ws + 37224448);               // 32768*1024*2 =  67,108,864 B
  float* att = (float*)(ws + 104333312);            // 32768*5*4    =     655,360 B
                                                    // total ~105 MB

  cvt_all<<<dim3(XBLOCKS + WBLOCKS), dim3(256), 0, stream>>>(X, Wq, Wk, cnnW, Xb, Wt1, Wt2);
  gemm_qk<<<dim3(2048), dim3(256), 0, stream>>>(Xb, Wt1, QKb);
  scores_att<<<dim3(NROW / 4), dim3(256), 0, stream>>>(QKb, vatt, att);
  gemm_out<<<dim3(1024), dim3(256), 0, stream>>>(Xb, Wt2, att, cnnb, out);
}

// Round 13
// 195.633 us; speedup vs baseline: 1.2433x; 1.0171x over previous
//
#include <hip/hip_runtime.h>
#include <stdint.h>
#include <stddef.h>

typedef unsigned short u16;
typedef __attribute__((ext_vector_type(8))) short s16x8;    // bf16 MFMA A/B frag (4 VGPR)
typedef __attribute__((ext_vector_type(8))) unsigned short u16x8;
typedef __attribute__((ext_vector_type(4))) unsigned short u16x4;
typedef __attribute__((ext_vector_type(4))) float f32x4;

typedef __attribute__((address_space(3))) void* as3_void_p;
typedef const __attribute__((address_space(1))) void* as1_cvoid_p;

#define GLD16(gp, lp) __builtin_amdgcn_global_load_lds((as1_cvoid_p)(gp), (as3_void_p)(lp), 16, 0, 0)

enum {
  NS = 2048, NF = 512, NH = 512, NW = 5,
  NROW = 32768,                    // B*S
  K2 = NW * NF,                    // 2560
  XBLOCKS = NROW * NF / 4 / 256,   // 16384
  W_ELEMS = 1024 * 512 + 512 * K2, // 1,835,008
  WBLOCKS = (W_ELEMS + 255) / 256  // 7168
};

__device__ __forceinline__ u16 f2bf(float f) {
  unsigned u = __float_as_uint(f);
  u += 0x7FFFu + ((u >> 16) & 1u);     // round-to-nearest-even
  return (u16)(u >> 16);
}
__device__ __forceinline__ float bf2f(u16 v) {
  return __uint_as_float(((unsigned)v) << 16);
}

// ---------------- merged conversion kernel ----------------

__global__ __launch_bounds__(256) void cvt_all(const float* __restrict__ X,
                                               const float* __restrict__ Wq,
                                               const float* __restrict__ Wk,
                                               const float* __restrict__ cnnW,
                                               u16* __restrict__ Xb,
                                               u16* __restrict__ Wt1,
                                               u16* __restrict__ Wt2) {
  int b = blockIdx.x;
  if (b < XBLOCKS) {
    int i = b * 256 + threadIdx.x;                 // 0 .. NROW*NF/4
    f32x4 v = ((const f32x4*)X)[i];
    u16x4 o;
    o.x = f2bf(v.x); o.y = f2bf(v.y); o.z = f2bf(v.z); o.w = f2bf(v.w);
    ((u16x4*)Xb)[i] = o;
  } else {
    int i = (b - XBLOCKS) * 256 + threadIdx.x;     // 0 .. W_ELEMS
    if (i >= W_ELEMS) return;
    if (i < 1024 * 512) {
      int j = i >> 9, f = i & 511;
      float v = (j < 512) ? Wq[(size_t)f * 512 + j] : Wk[(size_t)f * 512 + (j - 512)];
      Wt1[i] = f2bf(v);
    } else {
      int t = i - 1024 * 512;                      // < 512*2560
      int h = t / K2, k = t % K2;
      Wt2[t] = f2bf(cnnW[(size_t)k * 512 + h]);
    }
  }
}

// ---------------- GEMM1: QKb[n][0:1024] = Xb @ Wt1^T  (bf16 out) ----------------
// 128x128 block tile, 4 waves (2x2, wave tile 64x64), BK=64, single-buffer,
// 2-barrier K-step, 3 blocks/CU. T2 XOR-swizzle (rule #21).

__global__ __launch_bounds__(256, 3) void gemm_qk(const u16* __restrict__ Xb,
                                                  const u16* __restrict__ Wt1,
                                                  u16* __restrict__ QKb) {
  __shared__ u16 As[128 * 64];                     // 16 KB
  __shared__ u16 Bs[128 * 64];                     // 16 KB
  const int tid  = threadIdx.x;
  const int lane = tid & 63, wid = tid >> 6;
  const int wr = wid >> 1, wc = wid & 1;           // 2 x 2 wave grid, wave tile 64x64
  const int fr = lane & 15, fq = lane >> 4;
  // XCD-chunk swizzle: 2048 blocks, one XCD keeps contiguous row-panels
  const int wgid = (blockIdx.x & 7) * 256 + (blockIdx.x >> 3);
  const int brow = (wgid >> 3) * 128;
  const int bcol = (wgid & 7) * 128;

  // staging: 256 threads, 4 passes of 4KB per tile; row = p*32 + (tid>>3)
  const int rsub = tid >> 3;                                   // 0..31
  const int cbyte = (((tid & 7) ^ (rsub & 7)) << 4);           // swizzled source column byte
  const char* gA[4];
  const char* gB[4];
#pragma unroll
  for (int p = 0; p < 4; ++p) {
    gA[p] = (const char*)(Xb  + (size_t)(brow + p * 32 + rsub) * NF) + cbyte;
    gB[p] = (const char*)(Wt1 + (size_t)(bcol + p * 32 + rsub) * NF) + cbyte;
  }

  f32x4 acc[4][4] = {};

  for (int kt = 0; kt < 8; ++kt) {
    const int ko = kt * 128;
#pragma unroll
    for (int p = 0; p < 4; ++p) GLD16(gA[p] + ko, (char*)As + p * 4096 + tid * 16);
#pragma unroll
    for (int p = 0; p < 4; ++p) GLD16(gB[p] + ko, (char*)Bs + p * 4096 + tid * 16);
    __syncthreads();
#pragma unroll
    for (int kk = 0; kk < 2; ++kk) {
      s16x8 af[4], bfr[4];
#pragma unroll
      for (int m = 0; m < 4; ++m) {
        int row = wr * 64 + m * 16 + fr;
        af[m] = *(const s16x8*)((const char*)As + row * 128 + ((kk * 64 + fq * 16) ^ ((row & 7) << 4)));
      }
#pragma unroll
      for (int n = 0; n < 4; ++n) {
        int row = wc * 64 + n * 16 + fr;
        bfr[n] = *(const s16x8*)((const char*)Bs + row * 128 + ((kk * 64 + fq * 16) ^ ((row & 7) << 4)));
      }
#pragma unroll
      for (int m = 0; m < 4; ++m)
#pragma unroll
        for (int n = 0; n < 4; ++n)
          acc[m][n] = __builtin_amdgcn_mfma_f32_16x16x32_bf16(af[m], bfr[n], acc[m][n], 0, 0, 0);
    }
    __syncthreads();
  }

#pragma unroll
  for (int m = 0; m < 4; ++m)
#pragma unroll
    for (int n = 0; n < 4; ++n)
#pragma unroll
      for (int r = 0; r < 4; ++r) {
        int row = brow + wr * 64 + m * 16 + fq * 4 + r;
        int col = bcol + wc * 64 + n * 16 + fr;
        QKb[(size_t)row * 1024 + col] = f2bf(acc[m][n][r]);
      }
}

// ---------------- scores + softmax -> att[n][5] ----------------
// one wave per row n, h = lane*8..+7 vectorized. tanh via 1 - 2/(e^{2x}+1):
// overflow-graceful (e->inf => tanh->1), no clamp needed. XCD-chunked grid.

__global__ __launch_bounds__(256) void scores_att(const u16* __restrict__ QKb,
                                                  const float* __restrict__ vatt,
                                                  float* __restrict__ att) {
  const int lane = threadIdx.x & 63;
  const int wid  = threadIdx.x >> 6;
  const int wgid = (blockIdx.x & 7) * 1024 + (blockIdx.x >> 3);   // 8192 blocks chunked
  const int n = wgid * 4 + wid;
  const int s = n & (NS - 1);
  const int h0 = lane * 8;

  u16x8 qv = *(const u16x8*)(QKb + (size_t)n * 1024 + h0);
  f32x4 va0 = *(const f32x4*)(vatt + h0);
  f32x4 va1 = *(const f32x4*)(vatt + h0 + 4);
  float q[8], vv[8];
#pragma unroll
  for (int j = 0; j < 8; ++j) q[j] = bf2f(qv[j]);
  vv[0] = va0.x; vv[1] = va0.y; vv[2] = va0.z; vv[3] = va0.w;
  vv[4] = va1.x; vv[5] = va1.y; vv[6] = va1.z; vv[7] = va1.w;

  float sc[5];
#pragma unroll
  for (int w = 0; w < 5; ++w) {
    int sp = s + w - 2;
    u16x8 kv = {0, 0, 0, 0, 0, 0, 0, 0};
    if (sp >= 0 && sp < NS)
      kv = *(const u16x8*)(QKb + (size_t)(n + w - 2) * 1024 + 512 + h0);
    float acc = 0.f;
#pragma unroll
    for (int j = 0; j < 8; ++j) {
      float x = q[j] + bf2f(kv[j]);
      float e = __expf(2.f * x);                  // inf-safe below
      float r = __frcp_rn(e + 1.f);               // 1/(e+1); rcp(inf)=0
      acc += vv[j] * __builtin_fmaf(-2.f, r, 1.f);  // v * tanh(x)
    }
    sc[w] = acc;
  }
#pragma unroll
  for (int w = 0; w < 5; ++w)
#pragma unroll
    for (int o = 32; o > 0; o >>= 1)
      sc[w] += __shfl_xor(sc[w], o, 64);

  if (lane == 0) {
    float m = sc[0];
#pragma unroll
    for (int w = 1; w < 5; ++w) m = fmaxf(m, sc[w]);
    float e[5], sum = 0.f;
#pragma unroll
    for (int w = 0; w < 5; ++w) { e[w] = __expf(sc[w] - m); sum += e[w]; }
    float inv = 1.f / sum;
#pragma unroll
    for (int w = 0; w < 5; ++w) att[(size_t)n * 5 + w] = e[w] * inv;
  }
}

// ---------------- GEMM2 (fold + counted-vmcnt, compiler-scheduled interior) ----------------
// out[n][h] = b[h] + sum_w att[n][w]*(X[n+w-2]@W_w)[h]
// 128x128 block tile, 4 waves (2x2, wave tile 64x64), BK=64, double-buffered LDS,
// counted s_waitcnt vmcnt(8) keeps next tile's loads in flight across both raw barriers.
// Interior: ALL 16 frag loads issued, then ALL 32 MFMAs — no asm between, so the
// compiler emits incremental lgkmcnt(N) and overlaps ds_read latency with MFMAs.
// One lgkmcnt(0) before the trailing barrier guarantees reads retired before the
// other waves' GLD overwrite of this buffer.

__global__ __launch_bounds__(256, 2) void gemm_out(const u16* __restrict__ Xb,
                                                   const u16* __restrict__ Wt2,
                                                   const float* __restrict__ att,
                                                   const float* __restrict__ cnnb,
                                                   float* __restrict__ out) {
  __shared__ u16 As[2][128 * 64];                  // 2 x 16 KB
  __shared__ u16 Bs[2][128 * 64];                  // 2 x 16 KB
  __shared__ float att_s[128 * 5];
  const int tid  = threadIdx.x;
  const int lane = tid & 63, wid = tid >> 6;
  const int wr = wid >> 1, wc = wid & 1;           // 2 x 2 wave grid, wave tile 64x64
  const int fr = lane & 15, fq = lane >> 4;
  // XCD-chunk swizzle: 1024 blocks, contiguous row-panels per XCD (col-fast within)
  const int wgid = (blockIdx.x & 7) * 128 + (blockIdx.x >> 3);
  const int brow = (wgid >> 2) * 128;
  const int bcol = (wgid & 3) * 128;

  if (tid < 128) {
    int s = (brow + tid) & (NS - 1);
#pragma unroll
    for (int w = 0; w < 5; ++w) {
      int sp = s + w - 2;
      att_s[tid * 5 + w] = (sp >= 0 && sp < NS) ? att[(size_t)(brow + tid) * 5 + w] : 0.f;
    }
  }

  // staging: 256 threads, 4 passes of 4KB per tile; row = p*32 + (tid>>3)
  const int rsub = tid >> 3;                                   // 0..31
  const int cbyte = (((tid & 7) ^ (rsub & 7)) << 4);           // swizzled source column byte
  const char* gB[4];
#pragma unroll
  for (int p = 0; p < 4; ++p)
    gB[p] = (const char*)(Wt2 + (size_t)(bcol + p * 32 + rsub) * K2) + cbyte;

  // per-w A row base (clamped; invalid rows get fold weight 0)
  auto abase = [&](int w, int p) -> const char* {
    int g = brow + p * 32 + rsub + w - 2;
    g = g < 0 ? 0 : (g >= NROW ? NROW - 1 : g);
    return (const char*)(Xb + (size_t)g * NF) + cbyte;
  };

  f32x4 acc[4][4] = {};
  f32x4 accOut[4][4] = {};

  const char* gA[4];
#pragma unroll
  for (int p = 0; p < 4; ++p) gA[p] = abase(0, p);

  // prologue: stage (w=0, kt=0) into buf 0; single full drain (also covers att_s)
#pragma unroll
  for (int p = 0; p < 4; ++p) GLD16(gA[p], (char*)As[0] + p * 4096 + tid * 16);
#pragma unroll
  for (int p = 0; p < 4; ++p) GLD16(gB[p], (char*)Bs[0] + p * 4096 + tid * 16);
  __syncthreads();

  int cur = 0;
  for (int w = 0; w < 5; ++w) {
    const char* nA[4];
#pragma unroll
    for (int p = 0; p < 4; ++p) nA[p] = (w < 4) ? abase(w + 1, p) : gA[p];

    for (int kt = 0; kt < 8; ++kt) {
      const bool last = (w == 4) && (kt == 7);
      const int nb = cur ^ 1;
      if (!last) {
        char* ab = (char*)As[nb];
        char* bb = (char*)Bs[nb];
        if (kt < 7) {                              // stage (w, kt+1)
          const int ko = (kt + 1) * 128;
          const int kb = w * 1024 + (kt + 1) * 128;
#pragma unroll
          for (int p = 0; p < 4; ++p) GLD16(gA[p] + ko, ab + p * 4096 + tid * 16);
#pragma unroll
          for (int p = 0; p < 4; ++p) GLD16(gB[p] + kb, bb + p * 4096 + tid * 16);
        } else {                                   // stage (w+1, kt=0)
          const int kb = (w + 1) * 1024;
#pragma unroll
          for (int p = 0; p < 4; ++p) GLD16(nA[p], ab + p * 4096 + tid * 16);
#pragma unroll
          for (int p = 0; p < 4; ++p) GLD16(gB[p] + kb, bb + p * 4096 + tid * 16);
        }
        asm volatile("s_waitcnt vmcnt(8)" ::: "memory");   // tile t done; t+1 in flight
      } else {
        asm volatile("s_waitcnt vmcnt(0)" ::: "memory");   // final tile
      }
      __builtin_amdgcn_s_barrier();                // all waves have tile t in LDS

      const char* Ab = (const char*)As[cur];
      const char* Bb = (const char*)Bs[cur];
      // issue ALL frag loads, then ALL MFMAs — compiler fine-schedules lgkmcnt
      s16x8 af[2][4], bfr[2][4];
#pragma unroll
      for (int kk = 0; kk < 2; ++kk) {
#pragma unroll
        for (int m = 0; m < 4; ++m) {
          int row = wr * 64 + m * 16 + fr;
          af[kk][m] = *(const s16x8*)(Ab + row * 128 + ((kk * 64 + fq * 16) ^ ((row & 7) << 4)));
        }
#pragma unroll
        for (int n = 0; n < 4; ++n) {
          int row = wc * 64 + n * 16 + fr;
          bfr[kk][n] = *(const s16x8*)(Bb + row * 128 + ((kk * 64 + fq * 16) ^ ((row & 7) << 4)));
        }
      }
#pragma unroll
      for (int kk = 0; kk < 2; ++kk)
#pragma unroll
        for (int m = 0; m < 4; ++m)
#pragma unroll
          for (int n = 0; n < 4; ++n)
            acc[m][n] = __builtin_amdgcn_mfma_f32_16x16x32_bf16(af[kk][m], bfr[kk][n], acc[m][n], 0, 0, 0);

      if (kt == 7) {
        // fold: accOut += att[row][w] * acc; acc = 0  (registers + att_s only)
#pragma unroll
        for (int m = 0; m < 4; ++m) {
          float a0 = att_s[(wr * 64 + m * 16 + fq * 4 + 0) * 5 + w];
          float a1 = att_s[(wr * 64 + m * 16 + fq * 4 + 1) * 5 + w];
          float a2 = att_s[(wr * 64 + m * 16 + fq * 4 + 2) * 5 + w];
          float a3 = att_s[(wr * 64 + m * 16 + fq * 4 + 3) * 5 + w];
#pragma unroll
          for (int n = 0; n < 4; ++n) {
            accOut[m][n][0] += a0 * acc[m][n][0];
            accOut[m][n][1] += a1 * acc[m][n][1];
            accOut[m][n][2] += a2 * acc[m][n][2];
            accOut[m][n][3] += a3 * acc[m][n][3];
            acc[m][n] = f32x4{0.f, 0.f, 0.f, 0.f};
          }
        }
      }
      asm volatile("s_waitcnt lgkmcnt(0)" ::: "memory");  // reads retired (free: already 0)
      __builtin_amdgcn_s_barrier();                // buf reusable for GLD overwrite
      cur ^= 1;
    }
#pragma unroll
    for (int p = 0; p < 4; ++p) gA[p] = nA[p];
  }

#pragma unroll
  for (int m = 0; m < 4; ++m)
#pragma unroll
    for (int n = 0; n < 4; ++n)
#pragma unroll
      for (int r = 0; r < 4; ++r) {
        int row = brow + wr * 64 + m * 16 + fq * 4 + r;
        int col = bcol + wc * 64 + n * 16 + fr;
        out[(size_t)row * NH + col] = accOut[m][n][r] + cnnb[col];
      }
}

// ---------------- launch ----------------

extern "C" void kernel_launch(void* const* d_in, const int* in_sizes, int n_in,
                              void* d_out, int out_size, void* d_ws, size_t ws_size,
                              hipStream_t stream) {
  const float* X    = (const float*)d_in[0];
  const float* Wq   = (const float*)d_in[1];
  const float* Wk   = (const float*)d_in[2];
  const float* vatt = (const float*)d_in[3];
  const float* cnnW = (const float*)d_in[4];
  const float* cnnb = (const float*)d_in[5];
  float* out = (float*)d_out;

  char* ws = (char*)d_ws;
  u16*   Xb  = (u16*)ws;                            // 32768*512*2  =  33,554,432 B
  u16*   Wt1 = (u16*)(ws + 33554432);               // 1024*512*2   =   1,048,576 B
  u16*   Wt2 = (u16*)(ws + 34603008);               // 512*2560*2   =   2,621,440 B
  u16*   QKb = (u16*)(ws + 37224448);               // 32768*1024*2 =  67,108,864 B
  float* att = (float*)(ws + 104333312);            // 32768*5*4    =     655,360 B
                                                    // total ~105 MB

  cvt_all<<<dim3(XBLOCKS + WBLOCKS), dim3(256), 0, stream>>>(X, Wq, Wk, cnnW, Xb, Wt1, Wt2);
  gemm_qk<<<dim3(2048), dim3(256), 0, stream>>>(Xb, Wt1, QKb);
  scores_att<<<dim3(NROW / 4), dim3(256), 0, stream>>>(QKb, vatt, att);
  gemm_out<<<dim3(1024), dim3(256), 0, stream>>>(Xb, Wt2, att, cnnb, out);
}